// Round 1
// 239.053 us; speedup vs baseline: 1.1089x; 1.1089x over previous
//
#include <hip/hip_runtime.h>
#include <math.h>

#ifndef M_PI
#define M_PI 3.14159265358979323846
#endif

#define NAANG 1152
#define NDET  736
#define NPIX  512
#define PADN  2048
#define NHALF 1025   // PADN/2 + 1

// ---- workspace layout (byte offsets) ----
// float  cosT[2048]            @ 0        (8192 B)  cos(2*pi*r/2048)
// float  filt_f[1025]          @ 8192     (4100 B, pad 4224)
// float  h[2048]               @ 12416    (8192 B)  [pi/(2NA) scale folded]
// float4 trig[1152]            @ 20608    (18432 B) (cb, sb, K*cb, K*sb)
// float  filtered[1152*736]    @ 39040    (3391488 B)
// float  partial[NCH*512*512]  @ 3430528  (NCH MiB)
#define OFF_COST  0
#define OFF_FILTF 8192
#define OFF_H     12416
#define OFF_TRIG  20608
#define OFF_FS    39040
#define OFF_PART  3430528

// Raw buffer load with hardware bounds check: OOB (voffset+4 > num_records,
// including negative voffset seen as huge unsigned) returns 0.0f. This gives
// the reference's `valid ? v : 0` masking for free (no clamp/cmp/cndmask).
typedef int int32x4_t __attribute__((ext_vector_type(4)));
__device__ float llvm_amdgcn_raw_buffer_load_fp32(int32x4_t srsrc, int voffset,
                                                  int soffset, int glc_slc)
    __asm("llvm.amdgcn.raw.buffer.load.f32");

// ---------------------------------------------------------------------------
// Kernel 0: cos table, small args only (fast path). cosT[r] = cos(2*pi*r/2048)
// ---------------------------------------------------------------------------
__global__ void costab_kernel(float* __restrict__ cosT) {
    int r = blockIdx.x * 256 + threadIdx.x;   // 0..2047
    cosT[r] = (float)cos(2.0 * M_PI * (double)r / (double)PADN);
}

// ---------------------------------------------------------------------------
// Kernel 1: FILT[m] via table: cos(2pi*m*(2j+1)/2048) = cosT[(m*(2j+1))&2047]
// ---------------------------------------------------------------------------
__global__ void filt_spec_kernel(const float* __restrict__ cosT,
                                 float* __restrict__ filt_f) {
    __shared__ float red[256];
    const int m = blockIdx.x;          // 0..1024
    const int t = threadIdx.x;
    float s = 0.f;
    for (int j = t; j < 1024; j += 256) {
        int n = (j < 512) ? (2 * j + 1) : (2047 - 2 * j);
        float fj = (float)(-1.0 / ((M_PI * n) * (M_PI * n)));
        s += fj * cosT[(m * (2 * j + 1)) & (PADN - 1)];
    }
    red[t] = s;
    __syncthreads();
    for (int w = 128; w > 0; w >>= 1) {
        if (t < w) red[t] += red[t + w];
        __syncthreads();
    }
    if (t == 0) {
        double four = 2.0 * (0.25 + (double)red[0]);
        if (m > 0) {
            double om = M_PI * (double)m / (double)PADN;
            four *= sin(om) / om;      // small arg, fast path
        }
        filt_f[m] = (float)four;
    }
}

// ---------------------------------------------------------------------------
// Kernel 2: h[k] = irfft(FILT,2048)[k] * pi/(2*NA) via table lookups;
// blocks k<1152 also fill the trig table on lane 0 (small-arg double trig).
// ---------------------------------------------------------------------------
__global__ void h_kernel(const float* __restrict__ cosT,
                         const float* __restrict__ filt_f,
                         float* __restrict__ h, float4* __restrict__ trig) {
    __shared__ float red[256];
    const int k = blockIdx.x;          // 0..2047
    const int t = threadIdx.x;
    if (t == 0 && k < NAANG) {
        double ang = 2.0 * M_PI * (double)k / (double)NAANG + M_PI / 2.0;
        double c = cos(ang), s = sin(ang);
        double K = 1085.6 / 1.2858;    // DSD/DU (vox scaling cancels)
        trig[k] = make_float4((float)c, (float)s, (float)(K * c), (float)(K * s));
    }
    float s = 0.f;
    for (int m = t; m <= 1024; m += 256) {
        float F = filt_f[m];
        float c;
        if (m == 0) c = 1.f;
        else if (m == 1024) c = (k & 1) ? -1.f : 1.f;
        else c = 2.f * cosT[(m * k) & (PADN - 1)];
        s += F * c;
    }
    red[t] = s;
    __syncthreads();
    for (int w = 128; w > 0; w >>= 1) {
        if (t < w) red[t] += red[t + w];
        __syncthreads();
    }
    if (t == 0)
        h[k] = (float)((double)red[0] / (double)PADN * (M_PI / (2.0 * (double)NAANG)));
}

// ---------------------------------------------------------------------------
// Kernel 3: circular convolution, aligned-b128 form (unchanged, passing).
// ---------------------------------------------------------------------------
__global__ void conv_kernel(const float* __restrict__ x,
                            const float* __restrict__ h,
                            float* __restrict__ fs) {
    __shared__ float sh2[2816];        // h duplicated: sh2[i] = h[i & 2047]
    __shared__ float srow[NDET];
    const int row = blockIdx.x;
    const int t = threadIdx.x;
    const float4* h4 = (const float4*)h;
    for (int i = t; i < 704; i += 192) ((float4*)sh2)[i] = h4[i & 511];
    const float4* x4 = (const float4*)(x + row * NDET);
    for (int i = t; i < NDET / 4; i += 192) ((float4*)srow)[i] = x4[i];
    __syncthreads();

    const int t4 = 4 * t;
    float o0 = 0.f, o1 = 0.f, o2 = 0.f, o3 = 0.f;
    #pragma unroll 2
    for (int j = 0; j < NDET; j += 4) {
        float4 r4 = *(const float4*)&srow[j];
        const int A = t4 + PADN - j;
        float4 hlo = *(const float4*)&sh2[A - 4];
        float4 hhi = *(const float4*)&sh2[A];
        o0 = fmaf(r4.x, hhi.x, o0); o0 = fmaf(r4.y, hlo.w, o0);
        o0 = fmaf(r4.z, hlo.z, o0); o0 = fmaf(r4.w, hlo.y, o0);
        o1 = fmaf(r4.x, hhi.y, o1); o1 = fmaf(r4.y, hhi.x, o1);
        o1 = fmaf(r4.z, hlo.w, o1); o1 = fmaf(r4.w, hlo.z, o1);
        o2 = fmaf(r4.x, hhi.z, o2); o2 = fmaf(r4.y, hhi.y, o2);
        o2 = fmaf(r4.z, hhi.x, o2); o2 = fmaf(r4.w, hlo.w, o2);
        o3 = fmaf(r4.x, hhi.w, o3); o3 = fmaf(r4.y, hhi.z, o3);
        o3 = fmaf(r4.z, hhi.y, o3); o3 = fmaf(r4.w, hhi.x, o3);
    }
    if (t < NDET / 4)
        *(float4*)&fs[row * NDET + t4] = make_float4(o0, o1, o2, o3);
}

// ---------------------------------------------------------------------------
// Kernel 4: fan-beam backprojection — manual 2-deep software pipeline.
// Stage GEO(a): geometry + issue 8 bounds-checked buffer gathers (ping-pong
// A/B register sets); CONSUME(a) runs while GEO(a+1)'s loads are in flight.
// Per-angle SRD pair (base=row / base=row+4, num_records=735*4): hardware
// bounds check zeroes BOTH taps of any invalid ray (i0<0 or i0>734), exactly
// reproducing the reference's `valid` mask with zero VALU cost — no clamps,
// no cndmask, 32-bit voffset addressing (single v_lshlrev per gather).
// Fan weight uses w=r*r; the constant Dg^2 is folded into combine's scale.
// 4 pixels/thread (adjacent y): den_k chained subs, kpe_k chained adds.
// grid (2, 128, NCH); NCH=8 -> 2048 blocks = 8/CU * 4 waves = 32 waves/CU.
// ---------------------------------------------------------------------------
#define GEO(AA, G0L,G0H,G1L,G1H,G2L,G2H,G3L,G3H, FR0,FR1,FR2,FR3, W0,W1,W2,W3) \
  {                                                                      \
    float4 q = trig[abase + (AA)];   /* uniform -> scalar load */        \
    const float* rp_ = fs + (size_t)(abase + (AA)) * NDET;               \
    uintptr_t ua_ = (uintptr_t)rp_;                                      \
    int32x4_t sA_ = { (int)ua_, (int)(ua_ >> 32), 2940, 0x00020000 };    \
    uintptr_t ub_ = ua_ + 4;                                             \
    int32x4_t sB_ = { (int)ub_, (int)(ub_ >> 32), 2940, 0x00020000 };    \
    float den0 = fmaf(-xs, q.x, fmaf(-ys0, q.y, Dg));                    \
    float kpe0 = fmaf(ys0, q.z, -(xs * q.w));                            \
    float den1 = den0 - q.y, den2 = den1 - q.y, den3 = den2 - q.y;       \
    float kpe1 = kpe0 + q.z, kpe2 = kpe1 + q.z, kpe3 = kpe2 + q.z;       \
    float r0 = __builtin_amdgcn_rcpf(den0);                              \
    float r1 = __builtin_amdgcn_rcpf(den1);                              \
    float r2 = __builtin_amdgcn_rcpf(den2);                              \
    float r3 = __builtin_amdgcn_rcpf(den3);                              \
    float iu0 = fmaf(kpe0, r0, 367.5f);                                  \
    float iu1 = fmaf(kpe1, r1, 367.5f);                                  \
    float iu2 = fmaf(kpe2, r2, 367.5f);                                  \
    float iu3 = fmaf(kpe3, r3, 367.5f);                                  \
    float f0 = floorf(iu0), f1 = floorf(iu1);                            \
    float f2 = floorf(iu2), f3 = floorf(iu3);                            \
    int v0_ = ((int)f0) << 2;                                            \
    int v1_ = ((int)f1) << 2;                                            \
    int v2_ = ((int)f2) << 2;                                            \
    int v3_ = ((int)f3) << 2;                                            \
    G0L = llvm_amdgcn_raw_buffer_load_fp32(sA_, v0_, 0, 0);              \
    G0H = llvm_amdgcn_raw_buffer_load_fp32(sB_, v0_, 0, 0);              \
    G1L = llvm_amdgcn_raw_buffer_load_fp32(sA_, v1_, 0, 0);              \
    G1H = llvm_amdgcn_raw_buffer_load_fp32(sB_, v1_, 0, 0);              \
    G2L = llvm_amdgcn_raw_buffer_load_fp32(sA_, v2_, 0, 0);              \
    G2H = llvm_amdgcn_raw_buffer_load_fp32(sB_, v2_, 0, 0);              \
    G3L = llvm_amdgcn_raw_buffer_load_fp32(sA_, v3_, 0, 0);              \
    G3H = llvm_amdgcn_raw_buffer_load_fp32(sB_, v3_, 0, 0);              \
    FR0 = iu0 - f0; FR1 = iu1 - f1; FR2 = iu2 - f2; FR3 = iu3 - f3;      \
    W0 = r0 * r0; W1 = r1 * r1; W2 = r2 * r2; W3 = r3 * r3;              \
  }

#define CONSUME(G0L,G0H,G1L,G1H,G2L,G2H,G3L,G3H, FR0,FR1,FR2,FR3, W0,W1,W2,W3) \
  {                                                                      \
    float v0 = fmaf(FR0, G0H - G0L, G0L);                                \
    float v1 = fmaf(FR1, G1H - G1L, G1L);                                \
    float v2 = fmaf(FR2, G2H - G2L, G2L);                                \
    float v3 = fmaf(FR3, G3H - G3L, G3L);                                \
    acc0 = fmaf(W0, v0, acc0); acc1 = fmaf(W1, v1, acc1);                \
    acc2 = fmaf(W2, v2, acc2); acc3 = fmaf(W3, v3, acc3);                \
  }

template<int NCH>
__global__ __launch_bounds__(256, 8)
void backproj_kernel(const float* __restrict__ fs,
                     const float4* __restrict__ trig,
                     float* __restrict__ partial) {
    constexpr int ACL = NAANG / NCH;   // 144 for NCH=8 (even for all NCH used)
    const int t = threadIdx.x;
    const int abase = blockIdx.z * ACL;
    const int ix = blockIdx.x * 256 + t;
    const int iy = blockIdx.y * 4;
    const float xs  = (float)ix - 255.5f;
    const float ys0 = (float)iy - 255.5f;
    const float Dg = 850.0f;           // 595/0.7 exactly

    float acc0 = 0.f, acc1 = 0.f, acc2 = 0.f, acc3 = 0.f;
    float Ag0l, Ag0h, Ag1l, Ag1h, Ag2l, Ag2h, Ag3l, Ag3h;
    float Bg0l, Bg0h, Bg1l, Bg1h, Bg2l, Bg2h, Bg3l, Bg3h;
    float Af0, Af1, Af2, Af3, Aw0, Aw1, Aw2, Aw3;
    float Bf0, Bf1, Bf2, Bf3, Bw0, Bw1, Bw2, Bw3;

    GEO(0, Ag0l,Ag0h,Ag1l,Ag1h,Ag2l,Ag2h,Ag3l,Ag3h, Af0,Af1,Af2,Af3, Aw0,Aw1,Aw2,Aw3);
    int a = 0;
    for (; a + 2 < ACL; a += 2) {
        GEO(a + 1, Bg0l,Bg0h,Bg1l,Bg1h,Bg2l,Bg2h,Bg3l,Bg3h, Bf0,Bf1,Bf2,Bf3, Bw0,Bw1,Bw2,Bw3);
        CONSUME(Ag0l,Ag0h,Ag1l,Ag1h,Ag2l,Ag2h,Ag3l,Ag3h, Af0,Af1,Af2,Af3, Aw0,Aw1,Aw2,Aw3);
        GEO(a + 2, Ag0l,Ag0h,Ag1l,Ag1h,Ag2l,Ag2h,Ag3l,Ag3h, Af0,Af1,Af2,Af3, Aw0,Aw1,Aw2,Aw3);
        CONSUME(Bg0l,Bg0h,Bg1l,Bg1h,Bg2l,Bg2h,Bg3l,Bg3h, Bf0,Bf1,Bf2,Bf3, Bw0,Bw1,Bw2,Bw3);
    }
    GEO(ACL - 1, Bg0l,Bg0h,Bg1l,Bg1h,Bg2l,Bg2h,Bg3l,Bg3h, Bf0,Bf1,Bf2,Bf3, Bw0,Bw1,Bw2,Bw3);
    CONSUME(Ag0l,Ag0h,Ag1l,Ag1h,Ag2l,Ag2h,Ag3l,Ag3h, Af0,Af1,Af2,Af3, Aw0,Aw1,Aw2,Aw3);
    CONSUME(Bg0l,Bg0h,Bg1l,Bg1h,Bg2l,Bg2h,Bg3l,Bg3h, Bf0,Bf1,Bf2,Bf3, Bw0,Bw1,Bw2,Bw3);

    float* outp = partial + ((size_t)blockIdx.z * NPIX + iy) * NPIX + ix;
    outp[0 * NPIX] = acc0;
    outp[1 * NPIX] = acc1;
    outp[2 * NPIX] = acc2;
    outp[3 * NPIX] = acc3;
}

// ---------------------------------------------------------------------------
// Kernel 5: sum partials + HU window. Dg^2 (=722500) fan-weight constant is
// folded into the output scale (backproj accumulates r^2 * v).
// ---------------------------------------------------------------------------
template<int NCH>
__global__ void combine_kernel(const float* __restrict__ partial,
                               float* __restrict__ out) {
    int p = blockIdx.x * 256 + threadIdx.x;
    float s = 0.f;
    #pragma unroll
    for (int c = 0; c < NCH; ++c) s += partial[c * NPIX * NPIX + p];
    // Dg^2 * (1000/0.0192/4096); offset 24/4096 = 0.005859375
    out[p] = fmaf(s, (float)(722500.0 * 1000.0 / 0.0192 / 4096.0), 0.005859375f);
}

extern "C" void kernel_launch(void* const* d_in, const int* in_sizes, int n_in,
                              void* d_out, int out_size, void* d_ws, size_t ws_size,
                              hipStream_t stream) {
    const float* x = (const float*)d_in[0];     // (1,1,1152,736) fp32 sinogram
    float* out = (float*)d_out;                 // (1,1,512,512) fp32

    char* ws = (char*)d_ws;
    float*  cosT   = (float*)(ws + OFF_COST);
    float*  filt_f = (float*)(ws + OFF_FILTF);
    float*  h      = (float*)(ws + OFF_H);
    float4* trig   = (float4*)(ws + OFF_TRIG);
    float*  fs     = (float*)(ws + OFF_FS);
    float*  part   = (float*)(ws + OFF_PART);

    costab_kernel<<<PADN / 256, 256, 0, stream>>>(cosT);
    filt_spec_kernel<<<NHALF, 256, 0, stream>>>(cosT, filt_f);
    h_kernel<<<PADN, 256, 0, stream>>>(cosT, filt_f, h, trig);
    conv_kernel<<<NAANG, 192, 0, stream>>>(x, h, fs);

    const size_t pbytes = (size_t)NPIX * NPIX * 4;
    if (ws_size >= OFF_PART + 8 * pbytes) {
        backproj_kernel<8><<<dim3(2, 128, 8), 256, 0, stream>>>(fs, trig, part);
        combine_kernel<8><<<NPIX * NPIX / 256, 256, 0, stream>>>(part, out);
    } else if (ws_size >= OFF_PART + 4 * pbytes) {
        backproj_kernel<4><<<dim3(2, 128, 4), 256, 0, stream>>>(fs, trig, part);
        combine_kernel<4><<<NPIX * NPIX / 256, 256, 0, stream>>>(part, out);
    } else if (ws_size >= OFF_PART + 2 * pbytes) {
        backproj_kernel<2><<<dim3(2, 128, 2), 256, 0, stream>>>(fs, trig, part);
        combine_kernel<2><<<NPIX * NPIX / 256, 256, 0, stream>>>(part, out);
    } else {
        backproj_kernel<1><<<dim3(2, 128, 1), 256, 0, stream>>>(fs, trig, part);
        combine_kernel<1><<<NPIX * NPIX / 256, 256, 0, stream>>>(part, out);
    }
}